// Round 1
// baseline (217.667 us; speedup 1.0000x reference)
//
#include <hip/hip_runtime.h>
#include <hip/hip_bf16.h>
#include <stdint.h>

typedef __attribute__((ext_vector_type(4))) float f32x4;
typedef __attribute__((ext_vector_type(8))) __bf16 bf16x8;
typedef __attribute__((ext_vector_type(2))) unsigned int u32x2;
typedef __attribute__((ext_vector_type(4))) unsigned int u32x4;

#define N_NODES 16384
#define F_DIM   64
#define BM      64
#define BK      64

__device__ inline unsigned cvtpk_bf16(float lo, float hi) {
    unsigned r;
    asm("v_cvt_pk_bf16_f32 %0, %1, %2" : "=v"(r) : "v"(lo), "v"(hi));
    return r;
}

// ---------------------------------------------------------------------------
// Kernel A: h = input @ W  (fp32 compute), stored as bf16 in MFMA B-fragment
// packed layout: chunk[(kb*4 + ct)*64 + l] (16B) = h[kb*32 + (l>>4)*8 + j][ct*16 + (l&15)], j=0..7
// ---------------------------------------------------------------------------
__global__ __launch_bounds__(256) void dense_h(const float* __restrict__ inp,
                                               const float* __restrict__ W,
                                               short* __restrict__ hpack) {
    __shared__ float in_lds[64][64];
    __shared__ float wt_lds[64][68];   // W transposed [f][k], +4 pad breaks bank conflicts
    const int t = threadIdx.x;
    const int blk = blockIdx.x;        // nodes blk*64 ..

#pragma unroll
    for (int i = 0; i < 4; ++i) {      // load input tile 64x64 fp32
        int n = i * 256 + t; int row = n >> 4; int c = n & 15;
        f32x4 v = *(const f32x4*)(inp + (size_t)(blk * 64 + row) * 64 + c * 4);
        *(f32x4*)(&in_lds[row][c * 4]) = v;
    }
#pragma unroll
    for (int i = 0; i < 4; ++i) {      // load W, transpose into LDS
        int n = i * 256 + t; int k = n >> 4; int c = n & 15;
        f32x4 v = *(const f32x4*)(W + k * 64 + c * 4);
        wt_lds[c * 4 + 0][k] = v.x; wt_lds[c * 4 + 1][k] = v.y;
        wt_lds[c * 4 + 2][k] = v.z; wt_lds[c * 4 + 3][k] = v.w;
    }
    __syncthreads();

#pragma unroll
    for (int cc = 0; cc < 2; ++cc) {
        int c = cc * 256 + t;                 // chunk index within block, 0..511
        int kbL = c >> 8; int ct = (c >> 6) & 3; int l = c & 63;
        int f  = ct * 16 + (l & 15);
        int r0 = kbL * 32 + (l >> 4) * 8;
        float acc[8] = {0, 0, 0, 0, 0, 0, 0, 0};
        for (int k = 0; k < 64; k += 4) {
            f32x4 wv = *(const f32x4*)(&wt_lds[f][k]);
#pragma unroll
            for (int j = 0; j < 8; ++j) {
                f32x4 iv = *(const f32x4*)(&in_lds[r0 + j][k]);
                acc[j] += iv.x * wv.x + iv.y * wv.y + iv.z * wv.z + iv.w * wv.w;
            }
        }
        unsigned p0 = cvtpk_bf16(acc[0], acc[1]);
        unsigned p1 = cvtpk_bf16(acc[2], acc[3]);
        unsigned p2 = cvtpk_bf16(acc[4], acc[5]);
        unsigned p3 = cvtpk_bf16(acc[6], acc[7]);
        u32x4 w4 = {p0, p1, p2, p3};
        int kb = blk * 2 + kbL;
        *(u32x4*)(hpack + ((size_t)(kb * 4 + ct) * 64 + l) * 8) = w4;
    }
}

// ---------------------------------------------------------------------------
// Kernel B: partial[sp] = adj[:, k-range] @ h[k-range, :]
// 256 threads (4 waves), BM=64 rows, BK=64, double-buffered swizzled bf16 A-tile.
// Wave w owns rows 16w..16w+15 (all 64 cols): 8 mfma 16x16x32 per K-iter.
// ---------------------------------------------------------------------------
__global__ __launch_bounds__(256, 4) void spmm_adj(const float* __restrict__ adj,
                                                   const short* __restrict__ hp,
                                                   float* __restrict__ out,
                                                   const float* __restrict__ bias) {
    const int rb  = blockIdx.x;
    const int sp  = blockIdx.y;
    const int nsp = gridDim.y;
    const int kspan = N_NODES / nsp;
    const int iters = kspan / BK;
    const int k0    = sp * kspan;
    const int t  = threadIdx.x;
    const int wv = t >> 6;
    const int ln = t & 63;

    __shared__ short At[2][BM * BK];    // bf16, XOR-swizzled, 8KB each

    const size_t rowbase = (size_t)(rb * BM) * N_NODES;

    auto ldA = [&](int tt, f32x4* rv) {
        size_t base = rowbase + (size_t)(k0 + tt * BK);
#pragma unroll
        for (int i = 0; i < 4; ++i) {
            int n = i * 256 + t; int row = n >> 4; int c = n & 15;
            rv[i] = *(const f32x4*)(adj + base + (size_t)row * N_NODES + c * 4);
        }
    };
    auto stA = [&](int buf, const f32x4* rv) {
#pragma unroll
        for (int i = 0; i < 4; ++i) {
            int n = i * 256 + t; int row = n >> 4; int c = n & 15;
            unsigned lo = cvtpk_bf16(rv[i].x, rv[i].y);
            unsigned hi = cvtpk_bf16(rv[i].z, rv[i].w);
            int byte = row * 128 + ((c * 8) ^ ((row & 7) << 4));
            u32x2 w = {lo, hi};
            *(u32x2*)((char*)At[buf] + byte) = w;
        }
    };

    f32x4 acc[4] = {{0,0,0,0},{0,0,0,0},{0,0,0,0},{0,0,0,0}};
    const int arow  = wv * 16 + (ln & 15);
    const int abase = arow * 128;
    const int axor  = (ln & 7) << 4;
    const int koff  = (ln >> 4) * 16;     // byte offset of this lane's 8 bf16

    f32x4 rv[4];
    ldA(0, rv);
    stA(0, rv);

    for (int tt = 0; tt < iters; ++tt) {
        const int cur = tt & 1;
        const bool more = (tt + 1 < iters);
        if (more) ldA(tt + 1, rv);                     // prefetch: stays in flight across barrier
        asm volatile("s_waitcnt lgkmcnt(0)" ::: "memory");
        __builtin_amdgcn_s_barrier();                  // raw barrier: no vmcnt drain
#pragma unroll
        for (int ks2 = 0; ks2 < 2; ++ks2) {
            bf16x8 a = *(const bf16x8*)((const char*)At[cur] + abase + ((ks2 * 64 + koff) ^ axor));
            const short* hbase = hp + ((size_t)((k0 >> 5) + tt * 2 + ks2) * 4) * 512;
#pragma unroll
            for (int ct = 0; ct < 4; ++ct) {
                bf16x8 b = *(const bf16x8*)(hbase + ct * 512 + ln * 8);
                acc[ct] = __builtin_amdgcn_mfma_f32_16x16x32_bf16(a, b, acc[ct], 0, 0, 0);
            }
        }
        if (more) stA(cur ^ 1, rv);
    }

    // epilogue: C layout col=lane&15, row=(lane>>4)*4+j
    float* o = out + (size_t)sp * ((size_t)N_NODES * F_DIM);
    const int orow0 = rb * BM + wv * 16 + (ln >> 4) * 4;
    const int col   = ln & 15;
#pragma unroll
    for (int ct = 0; ct < 4; ++ct) {
#pragma unroll
        for (int j = 0; j < 4; ++j) {
            float v = acc[ct][j];
            if (bias) v += bias[ct * 16 + col];
            o[(size_t)(orow0 + j) * F_DIM + ct * 16 + col] = v;
        }
    }
}

// ---------------------------------------------------------------------------
// Kernel C: out = sum_i partial[i] + bias
// ---------------------------------------------------------------------------
__global__ __launch_bounds__(256) void reduce_add(const float* __restrict__ part,
                                                  const float* __restrict__ bias,
                                                  float* __restrict__ out, int nsp) {
    int g = blockIdx.x * 256 + threadIdx.x;      // 0..262143, 4 floats each
    f32x4 s = {0, 0, 0, 0};
    for (int i = 0; i < nsp; ++i)
        s += *(const f32x4*)(part + (size_t)i * ((size_t)N_NODES * F_DIM) + (size_t)g * 4);
    f32x4 bv = *(const f32x4*)(bias + ((g * 4) & 63));
    *(f32x4*)(out + (size_t)g * 4) = s + bv;
}

extern "C" void kernel_launch(void* const* d_in, const int* in_sizes, int n_in,
                              void* d_out, int out_size, void* d_ws, size_t ws_size,
                              hipStream_t stream) {
    const float* inp = (const float*)d_in[0];
    const float* adj = (const float*)d_in[1];
    const float* W   = (const float*)d_in[2];
    const float* b   = (const float*)d_in[3];
    float* out = (float*)d_out;

    char*  ws = (char*)d_ws;
    const size_t HP = (size_t)N_NODES * F_DIM * sizeof(short);      // 2 MB bf16 packed h
    short* hpack = (short*)ws;
    float* partial = (float*)(ws + HP);
    const size_t P1 = (size_t)N_NODES * F_DIM * sizeof(float);      // 4 MB per partial

    dense_h<<<N_NODES / 64, 256, 0, stream>>>(inp, W, hpack);

    if (ws_size >= HP + 4 * P1) {
        dim3 g(N_NODES / BM, 4);
        spmm_adj<<<g, 256, 0, stream>>>(adj, hpack, partial, nullptr);
        reduce_add<<<(N_NODES * F_DIM) / 1024, 256, 0, stream>>>(partial, b, out, 4);
    } else if (ws_size >= HP + P1) {
        dim3 g(N_NODES / BM, 1);
        spmm_adj<<<g, 256, 0, stream>>>(adj, hpack, partial, nullptr);
        reduce_add<<<(N_NODES * F_DIM) / 1024, 256, 0, stream>>>(partial, b, out, 1);
    } else {
        dim3 g(N_NODES / BM, 1);
        spmm_adj<<<g, 256, 0, stream>>>(adj, hpack, out, b);
    }
}